// Round 1
// baseline (519.583 us; speedup 1.0000x reference)
//
#include <hip/hip_runtime.h>
#include <stdint.h>

typedef int int32x4 __attribute__((ext_vector_type(4)));

#define M_ROWS 8192
#define K_DIM  4096
#define N_DIM  4096

#define GPTR(p) ((const __attribute__((address_space(1))) unsigned int*)(p))
#define LPTR(p) ((__attribute__((address_space(3))) unsigned int*)(p))

// ---------- shared helper: block-wide absmax over 256 threads ----------
__device__ __forceinline__ float block_absmax_256(float v, float* red) {
#pragma unroll
  for (int off = 32; off > 0; off >>= 1)
    v = fmaxf(v, __shfl_down(v, off, 64));
  const int w = threadIdx.x >> 6;
  if ((threadIdx.x & 63) == 0) red[w] = v;
  __syncthreads();
  return fmaxf(fmaxf(red[0], red[1]), fmaxf(red[2], red[3]));
}

// ---------- 1. per-row quantize x -> int8 + scale (lane-contiguous loads) ----------
__global__ void quant_x_kernel(const float* __restrict__ x,
                               int8_t* __restrict__ qx,
                               float* __restrict__ sx) {
  __shared__ float red[4];
  const int row = blockIdx.x;
  const int t = threadIdx.x;
  const float4* xr = (const float4*)(x + (size_t)row * K_DIM);
  float4 v[4];
  float m = 0.0f;
#pragma unroll
  for (int i = 0; i < 4; ++i) {
    v[i] = xr[i * 256 + t];  // instruction i: lanes contiguous 16 B -> coalesced
    m = fmaxf(m, fmaxf(fmaxf(fabsf(v[i].x), fabsf(v[i].y)),
                       fmaxf(fabsf(v[i].z), fabsf(v[i].w))));
  }
  float amax = block_absmax_256(m, red);
  float scale = amax / 127.0f;
  if (scale == 0.0f) scale = 1.0f;
  if (t == 0) sx[row] = scale;
  int* qw = (int*)(qx + (size_t)row * K_DIM);
#pragma unroll
  for (int i = 0; i < 4; ++i) {
    float a = fminf(fmaxf(v[i].x / scale, -127.0f), 127.0f);
    float b = fminf(fmaxf(v[i].y / scale, -127.0f), 127.0f);
    float c = fminf(fmaxf(v[i].z / scale, -127.0f), 127.0f);
    float d = fminf(fmaxf(v[i].w / scale, -127.0f), 127.0f);
    int qa = (int)rintf(a), qb = (int)rintf(b), qc = (int)rintf(c), qd = (int)rintf(d);
    qw[i * 256 + t] =
        (qa & 255) | ((qb & 255) << 8) | ((qc & 255) << 16) | ((qd & 255) << 24);
  }
}

// ---------- 2. per-column partial absmax of kernel (no atomics, no memset) ----------
__global__ void colmax_kernel(const float* __restrict__ k,
                              float* __restrict__ cmp) {
  const int c = blockIdx.x * 256 + threadIdx.x;
  const int r0 = blockIdx.y * 128;
  float m = 0.0f;
  for (int i = 0; i < 128; ++i)
    m = fmaxf(m, fabsf(k[(size_t)(r0 + i) * N_DIM + c]));
  cmp[(size_t)blockIdx.y * N_DIM + c] = m;  // partial max, reduced in finalize
}

// ---------- 3. finalize: reduce colmax partials -> sk; bias int16 fake-quant ----------
__global__ void finalize_kernel(const float* __restrict__ cmp,
                                float* __restrict__ sk,
                                const float* __restrict__ bias,
                                float* __restrict__ bq) {
  __shared__ float red[4];
  const int t = threadIdx.x;
  if (blockIdx.x < 16) {
    const int c = blockIdx.x * 256 + t;
    float m = 0.0f;
#pragma unroll
    for (int i = 0; i < 32; ++i) m = fmaxf(m, cmp[(size_t)i * N_DIM + c]);
    float s = m / 127.0f;
    if (s == 0.0f) s = 1.0f;
    sk[c] = s;
  } else {
    float4 v[4];
    float m = 0.0f;
#pragma unroll
    for (int i = 0; i < 4; ++i) {
      v[i] = *(const float4*)(bias + t * 16 + i * 4);
      m = fmaxf(m, fmaxf(fmaxf(fabsf(v[i].x), fabsf(v[i].y)),
                         fmaxf(fabsf(v[i].z), fabsf(v[i].w))));
    }
    float amax = block_absmax_256(m, red);
    float s = amax / 32767.0f;
    if (s == 0.0f) s = 1.0f;
#pragma unroll
    for (int i = 0; i < 4; ++i) {
      float4 o;
      o.x = rintf(fminf(fmaxf(v[i].x / s, -32767.0f), 32767.0f)) * s;
      o.y = rintf(fminf(fmaxf(v[i].y / s, -32767.0f), 32767.0f)) * s;
      o.z = rintf(fminf(fmaxf(v[i].z / s, -32767.0f), 32767.0f)) * s;
      o.w = rintf(fminf(fmaxf(v[i].w / s, -32767.0f), 32767.0f)) * s;
      *(float4*)(bq + t * 16 + i * 4) = o;
    }
  }
}

// ---------- 4. quantize kernel per-col and transpose -> qkT[F][D] int8 ----------
__global__ void quant_kT_kernel(const float* __restrict__ kern,
                                const float* __restrict__ sk,
                                int8_t* __restrict__ qkT) {
  __shared__ int8_t tile[64][80];
  const int t = threadIdx.x;
  const int c0 = blockIdx.x * 64;
  const int r0 = blockIdx.y * 64;
  const int colg = (t & 15) * 4;
  const int row = t >> 4;
  float s[4];
#pragma unroll
  for (int j = 0; j < 4; ++j) s[j] = sk[c0 + colg + j];
#pragma unroll
  for (int i = 0; i < 4; ++i) {
    const int r = row + i * 16;
    float4 v = *(const float4*)&kern[(size_t)(r0 + r) * N_DIM + c0 + colg];
    tile[colg + 0][r] = (int8_t)rintf(fminf(fmaxf(v.x / s[0], -127.0f), 127.0f));
    tile[colg + 1][r] = (int8_t)rintf(fminf(fmaxf(v.y / s[1], -127.0f), 127.0f));
    tile[colg + 2][r] = (int8_t)rintf(fminf(fmaxf(v.z / s[2], -127.0f), 127.0f));
    tile[colg + 3][r] = (int8_t)rintf(fminf(fmaxf(v.w / s[3], -127.0f), 127.0f));
  }
  __syncthreads();
  const int f = t >> 2;
  const int seg = (t & 3) * 16;
  int4 w = *(const int4*)&tile[f][seg];
  *(int4*)(qkT + (size_t)(c0 + f) * K_DIM + r0 + seg) = w;
}

// ---------- 5. int8 GEMM 8192x4096x4096 + scale/bias epilogue ----------
// 128x64 wave tile (acc 8x4), A-only LDS (double-buffered, BK=64, 32 KiB),
// B frags read direct from global (qkT is [N][K]: 16 fully-used 64B lines
// per b128-equivalent load -> moves B traffic off the LDS pipe), prefetch of
// next A-tile + next B-frags issued before the 32 MFMAs, ONE barrier/K-step.
#define BM 256
#define BN 128
#define BK 64

__global__ __launch_bounds__(256, 2)
void gemm_kernel(const int8_t* __restrict__ qx,
                 const int8_t* __restrict__ qkT,
                 const float* __restrict__ sx,
                 const float* __restrict__ sk,
                 const float* __restrict__ bq,
                 float* __restrict__ out) {
  __shared__ int32x4 AsV[2048];  // 32 KiB: 2 buffers x [256 rows][64 B]
  char* As = (char*)AsV;

  const int t = threadIdx.x;
  const int w = t >> 6;
  const int l = t & 63;
  const int wm = w >> 1, wn = w & 1;
  const int rowBase = blockIdx.y * BM;
  const int colBase = blockIdx.x * BN;

  // LDS holds global chunk p^(row&3) at phys chunk p (chunk = 16 B of K).
  // Staging (linear DMA dest): thread t -> row t>>2, phys chunk t&3, so it
  // must FETCH global chunk (t&3)^((t>>2)&3) (involution; Guideline 21).
  const int8_t* gA = qx + (size_t)(rowBase + (t >> 2)) * K_DIM
                        + (((t & 3) ^ ((t >> 2) & 3)) << 4);
  // B frag: lane l -> qkT row (output col) l&15, k-chunk l>>4.
  const int8_t* gB = qkT + (size_t)(colBase + wn * 64 + (l & 15)) * K_DIM
                         + ((l >> 4) << 4);

  // A frag read: row = wm*128 + mt*16 + (l&15) (row&3 == l&3), swizzled chunk.
  int aoff[8];
#pragma unroll
  for (int mt = 0; mt < 8; ++mt)
    aoff[mt] = (wm * 128 + mt * 16 + (l & 15)) * 64 + (((l >> 4) ^ (l & 3)) << 4);

  int32x4 zero = {0, 0, 0, 0};
  int32x4 acc[8][4];
#pragma unroll
  for (int mt = 0; mt < 8; ++mt)
#pragma unroll
    for (int nt = 0; nt < 4; ++nt) acc[mt][nt] = zero;

  int32x4 bc[4], bn[4];

  // prologue: stage tile k=0, load B frags k=0
#pragma unroll
  for (int j = 0; j < 4; ++j)
    __builtin_amdgcn_global_load_lds(GPTR(gA + (size_t)j * 64 * K_DIM),
                                     LPTR(As + j * 4096 + w * 1024), 16, 0, 0);
#pragma unroll
  for (int nt = 0; nt < 4; ++nt)
    bc[nt] = *(const int32x4*)(gB + (size_t)nt * 16 * K_DIM);
  __syncthreads();

  int buf = 0;
  for (int i = 0; i < 63; ++i) {
    const int kn = (i + 1) * BK;
    // issue next-tile A staging + next B frags BEFORE compute (latency hides
    // under the MFMA block; __syncthreads at the bottom is the only drain)
    char* dst = As + ((buf ^ 1) << 14) + w * 1024;
#pragma unroll
    for (int j = 0; j < 4; ++j)
      __builtin_amdgcn_global_load_lds(GPTR(gA + (size_t)j * 64 * K_DIM + kn),
                                       LPTR(dst + j * 4096), 16, 0, 0);
#pragma unroll
    for (int nt = 0; nt < 4; ++nt)
      bn[nt] = *(const int32x4*)(gB + (size_t)nt * 16 * K_DIM + kn);

    const char* Ab = As + (buf << 14);
    int32x4 af[8];
#pragma unroll
    for (int mt = 0; mt < 8; ++mt)
      af[mt] = *(const int32x4*)(Ab + aoff[mt]);
#pragma unroll
    for (int mt = 0; mt < 8; ++mt)
#pragma unroll
      for (int nt = 0; nt < 4; ++nt)
        acc[mt][nt] = __builtin_amdgcn_mfma_i32_16x16x64_i8(
            af[mt], bc[nt], acc[mt][nt], 0, 0, 0);

    __syncthreads();  // publishes buf^1 (vmcnt0) + protects buf reuse (lgkm0)
#pragma unroll
    for (int nt = 0; nt < 4; ++nt) bc[nt] = bn[nt];
    buf ^= 1;
  }
  {  // final K-step (k = 4032), no prefetch
    const char* Ab = As + (buf << 14);
    int32x4 af[8];
#pragma unroll
    for (int mt = 0; mt < 8; ++mt)
      af[mt] = *(const int32x4*)(Ab + aoff[mt]);
#pragma unroll
    for (int mt = 0; mt < 8; ++mt)
#pragma unroll
      for (int nt = 0; nt < 4; ++nt)
        acc[mt][nt] = __builtin_amdgcn_mfma_i32_16x16x64_i8(
            af[mt], bc[nt], acc[mt][nt], 0, 0, 0);
  }

  // epilogue: y = acc * sx[row] * sk[col] + bq[col]
  const int lr = (l >> 4) * 4;
  const int lc = l & 15;
  float skc[4], bqc[4];
#pragma unroll
  for (int nt = 0; nt < 4; ++nt) {
    const int c = colBase + wn * 64 + nt * 16 + lc;
    skc[nt] = sk[c];
    bqc[nt] = bq[c];
  }
#pragma unroll
  for (int mt = 0; mt < 8; ++mt) {
    const int r0 = rowBase + wm * 128 + mt * 16 + lr;
    float sxr[4];
#pragma unroll
    for (int r = 0; r < 4; ++r) sxr[r] = sx[r0 + r];
#pragma unroll
    for (int nt = 0; nt < 4; ++nt) {
      const int c = colBase + wn * 64 + nt * 16 + lc;
#pragma unroll
      for (int r = 0; r < 4; ++r)
        out[(size_t)(r0 + r) * N_DIM + c] =
            (float)acc[mt][nt][r] * (sxr[r] * skc[nt]) + bqc[nt];
    }
  }
}

// ---------- 6. per-row int8 requant of output (in place) ----------
__global__ void requant_kernel(float* __restrict__ y) {
  __shared__ float red[4];
  const int row = blockIdx.x;
  const int t = threadIdx.x;
  float* yr = y + (size_t)row * N_DIM;
  float4 v[4];
  float m = 0.0f;
#pragma unroll
  for (int i = 0; i < 4; ++i) {
    v[i] = *(const float4*)(yr + i * 1024 + t * 4);
    m = fmaxf(m, fmaxf(fmaxf(fabsf(v[i].x), fabsf(v[i].y)),
                       fmaxf(fabsf(v[i].z), fabsf(v[i].w))));
  }
  float amax = block_absmax_256(m, red);
  float s = amax / 127.0f;
  if (s == 0.0f) s = 1.0f;
#pragma unroll
  for (int i = 0; i < 4; ++i) {
    float4 o;
    o.x = rintf(fminf(fmaxf(v[i].x / s, -127.0f), 127.0f)) * s;
    o.y = rintf(fminf(fmaxf(v[i].y / s, -127.0f), 127.0f)) * s;
    o.z = rintf(fminf(fmaxf(v[i].z / s, -127.0f), 127.0f)) * s;
    o.w = rintf(fminf(fmaxf(v[i].w / s, -127.0f), 127.0f)) * s;
    *(float4*)(yr + i * 1024 + t * 4) = o;
  }
}

extern "C" void kernel_launch(void* const* d_in, const int* in_sizes, int n_in,
                              void* d_out, int out_size, void* d_ws, size_t ws_size,
                              hipStream_t stream) {
  (void)in_sizes; (void)n_in; (void)out_size; (void)ws_size;
  const float* x    = (const float*)d_in[0];
  const float* kern = (const float*)d_in[1];
  const float* bias = (const float*)d_in[2];
  float* out = (float*)d_out;

  char* w8 = (char*)d_ws;
  int8_t* qx  = (int8_t*)w8;                       // 32 MiB
  int8_t* qkT = (int8_t*)(w8 + 33554432);          // 16 MiB
  // cmp (512 KiB) overlaps qkT start: dead before quant_kT writes qkT
  float* cmp  = (float*)(w8 + 33554432);
  float* sx   = (float*)(w8 + 50331648);           // 8192 f
  float* sk   = (float*)(w8 + 50331648 + 32768);   // 4096 f
  float* bq   = (float*)(w8 + 50331648 + 49152);   // 4096 f

  quant_x_kernel<<<M_ROWS, 256, 0, stream>>>(x, qx, sx);
  colmax_kernel<<<dim3(16, 32), 256, 0, stream>>>(kern, cmp);
  finalize_kernel<<<17, 256, 0, stream>>>(cmp, sk, bias, bq);
  quant_kT_kernel<<<dim3(64, 64), 256, 0, stream>>>(kern, sk, qkT);
  gemm_kernel<<<dim3(N_DIM / BN, M_ROWS / BM), 256, 0, stream>>>(qx, qkT, sx, sk, bq, out);
  requant_kernel<<<M_ROWS, 256, 0, stream>>>(out);
}

// Round 2
// 484.953 us; speedup vs baseline: 1.0714x; 1.0714x over previous
//
#include <hip/hip_runtime.h>
#include <stdint.h>

typedef int int32x4  __attribute__((ext_vector_type(4)));
typedef int int32x16 __attribute__((ext_vector_type(16)));

#define M_ROWS 8192
#define K_DIM  4096
#define N_DIM  4096

#define GPTR(p) ((const __attribute__((address_space(1))) unsigned int*)(p))
#define LPTR(p) ((__attribute__((address_space(3))) unsigned int*)(p))

// ---------- shared helper: block-wide absmax over 256 threads ----------
__device__ __forceinline__ float block_absmax_256(float v, float* red) {
#pragma unroll
  for (int off = 32; off > 0; off >>= 1)
    v = fmaxf(v, __shfl_down(v, off, 64));
  const int w = threadIdx.x >> 6;
  if ((threadIdx.x & 63) == 0) red[w] = v;
  __syncthreads();
  return fmaxf(fmaxf(red[0], red[1]), fmaxf(red[2], red[3]));
}

// ---------- 1. per-row quantize x -> int8 + scale (lane-contiguous loads) ----------
__global__ void quant_x_kernel(const float* __restrict__ x,
                               int8_t* __restrict__ qx,
                               float* __restrict__ sx) {
  __shared__ float red[4];
  const int row = blockIdx.x;
  const int t = threadIdx.x;
  const float4* xr = (const float4*)(x + (size_t)row * K_DIM);
  float4 v[4];
  float m = 0.0f;
#pragma unroll
  for (int i = 0; i < 4; ++i) {
    v[i] = xr[i * 256 + t];  // lanes contiguous 16 B -> coalesced
    m = fmaxf(m, fmaxf(fmaxf(fabsf(v[i].x), fabsf(v[i].y)),
                       fmaxf(fabsf(v[i].z), fabsf(v[i].w))));
  }
  float amax = block_absmax_256(m, red);
  float scale = amax / 127.0f;
  if (scale == 0.0f) scale = 1.0f;
  if (t == 0) sx[row] = scale;
  int* qw = (int*)(qx + (size_t)row * K_DIM);
#pragma unroll
  for (int i = 0; i < 4; ++i) {
    float a = fminf(fmaxf(v[i].x / scale, -127.0f), 127.0f);
    float b = fminf(fmaxf(v[i].y / scale, -127.0f), 127.0f);
    float c = fminf(fmaxf(v[i].z / scale, -127.0f), 127.0f);
    float d = fminf(fmaxf(v[i].w / scale, -127.0f), 127.0f);
    int qa = (int)rintf(a), qb = (int)rintf(b), qc = (int)rintf(c), qd = (int)rintf(d);
    qw[i * 256 + t] =
        (qa & 255) | ((qb & 255) << 8) | ((qc & 255) << 16) | ((qd & 255) << 24);
  }
}

// ---------- 2. per-column partial absmax of kernel (no atomics, no memset) ----------
__global__ void colmax_kernel(const float* __restrict__ k,
                              float* __restrict__ cmp) {
  const int c = blockIdx.x * 256 + threadIdx.x;
  const int r0 = blockIdx.y * 128;
  float m = 0.0f;
  for (int i = 0; i < 128; ++i)
    m = fmaxf(m, fabsf(k[(size_t)(r0 + i) * N_DIM + c]));
  cmp[(size_t)blockIdx.y * N_DIM + c] = m;  // partial max, reduced in finalize
}

// ---------- 3. finalize: reduce colmax partials -> sk; bias int16 fake-quant ----------
__global__ void finalize_kernel(const float* __restrict__ cmp,
                                float* __restrict__ sk,
                                const float* __restrict__ bias,
                                float* __restrict__ bq) {
  __shared__ float red[4];
  const int t = threadIdx.x;
  if (blockIdx.x < 16) {
    const int c = blockIdx.x * 256 + t;
    float m = 0.0f;
#pragma unroll
    for (int i = 0; i < 32; ++i) m = fmaxf(m, cmp[(size_t)i * N_DIM + c]);
    float s = m / 127.0f;
    if (s == 0.0f) s = 1.0f;
    sk[c] = s;
  } else {
    float4 v[4];
    float m = 0.0f;
#pragma unroll
    for (int i = 0; i < 4; ++i) {
      v[i] = *(const float4*)(bias + t * 16 + i * 4);
      m = fmaxf(m, fmaxf(fmaxf(fabsf(v[i].x), fabsf(v[i].y)),
                         fmaxf(fabsf(v[i].z), fabsf(v[i].w))));
    }
    float amax = block_absmax_256(m, red);
    float s = amax / 32767.0f;
    if (s == 0.0f) s = 1.0f;
#pragma unroll
    for (int i = 0; i < 4; ++i) {
      float4 o;
      o.x = rintf(fminf(fmaxf(v[i].x / s, -32767.0f), 32767.0f)) * s;
      o.y = rintf(fminf(fmaxf(v[i].y / s, -32767.0f), 32767.0f)) * s;
      o.z = rintf(fminf(fmaxf(v[i].z / s, -32767.0f), 32767.0f)) * s;
      o.w = rintf(fminf(fmaxf(v[i].w / s, -32767.0f), 32767.0f)) * s;
      *(float4*)(bq + t * 16 + i * 4) = o;
    }
  }
}

// ---------- 4. quantize kernel per-col and transpose -> qkT[F][D] int8 ----------
__global__ void quant_kT_kernel(const float* __restrict__ kern,
                                const float* __restrict__ sk,
                                int8_t* __restrict__ qkT) {
  __shared__ int8_t tile[64][80];
  const int t = threadIdx.x;
  const int c0 = blockIdx.x * 64;
  const int r0 = blockIdx.y * 64;
  const int colg = (t & 15) * 4;
  const int row = t >> 4;
  float s[4];
#pragma unroll
  for (int j = 0; j < 4; ++j) s[j] = sk[c0 + colg + j];
#pragma unroll
  for (int i = 0; i < 4; ++i) {
    const int r = row + i * 16;
    float4 v = *(const float4*)&kern[(size_t)(r0 + r) * N_DIM + c0 + colg];
    tile[colg + 0][r] = (int8_t)rintf(fminf(fmaxf(v.x / s[0], -127.0f), 127.0f));
    tile[colg + 1][r] = (int8_t)rintf(fminf(fmaxf(v.y / s[1], -127.0f), 127.0f));
    tile[colg + 2][r] = (int8_t)rintf(fminf(fmaxf(v.z / s[2], -127.0f), 127.0f));
    tile[colg + 3][r] = (int8_t)rintf(fminf(fmaxf(v.w / s[3], -127.0f), 127.0f));
  }
  __syncthreads();
  const int f = t >> 2;
  const int seg = (t & 3) * 16;
  int4 w = *(const int4*)&tile[f][seg];
  *(int4*)(qkT + (size_t)(c0 + f) * K_DIM + r0 + seg) = w;
}

// ---------- 5. int8 GEMM 8192x4096x4096 + scale/bias epilogue ----------
// Round-0-proven skeleton (both tiles in LDS, 128-B rows, chunk^(row&7)
// swizzle, 2 barriers/K-step, width-16 DMA staging) with bigger wave tile:
// BM=256 x BN=128 block, 4 waves 2x2 -> 128x64 per wave (frag traffic
// 16->12 MiB/CU) and mfma_i32_32x32x32_i8 (4404 vs 3944 TOPS, half the
// MFMA + ds_read issue slots). LDS 48 KiB; VGPR ~190 -> 2 blocks/CU.
#define BM 256
#define BN 128
#define BK 128

__global__ __launch_bounds__(256, 2)
void gemm_kernel(const int8_t* __restrict__ qx,
                 const int8_t* __restrict__ qkT,
                 const float* __restrict__ sx,
                 const float* __restrict__ sk,
                 const float* __restrict__ bq,
                 float* __restrict__ out) {
  __shared__ int32x4 AsV[2048];  // 32 KiB: A tile [256 rows][128 B]
  __shared__ int32x4 BsV[1024];  // 16 KiB: B tile [128 cols][128 B]
  char* As = (char*)AsV;
  char* Bs = (char*)BsV;

  const int t = threadIdx.x;
  const int w = t >> 6;
  const int l = t & 63;
  const int wm = w >> 1, wn = w & 1;

  // XCD-chunked swizzle (1024 blocks, 1024%8==0): consecutive logical tiles
  // on one XCD, column-major so each XCD's B band (2 MiB) is L2-resident.
  const int b = blockIdx.y * gridDim.x + blockIdx.x;
  const int lb = (b & 7) * 128 + (b >> 3);
  const int rowBase = (lb & 31) * BM;   // 32 row-tiles
  const int colBase = (lb >> 5) * BN;   // 32 col-tiles

  // LDS: global k-chunk g (16 B) of row r lives at phys slot g ^ (r&7).
  // Linear DMA dest: thread t writes row t>>3, phys slot t&7 -> fetches
  // global chunk (t&7)^((t>>3)&7). Issue j advances 32 rows.
  const int8_t* gA = qx  + (size_t)(rowBase + (t >> 3)) * K_DIM
                         + (((t & 7) ^ ((t >> 3) & 7)) * 16);
  const int8_t* gB = qkT + (size_t)(colBase + (t >> 3)) * K_DIM
                         + (((t & 7) ^ ((t >> 3) & 7)) * 16);

  // Frag reads (32x32x32): lane l -> row l&31, 16-B chunk (2s + l>>5),
  // swizzled with row&7 == l&7. Each chunk slot gets exactly 8 lanes
  // -> bank-balanced (b128 minimum of 8 cy).
  int aoff[4], boff[2], soff[4];
#pragma unroll
  for (int mt = 0; mt < 4; ++mt)
    aoff[mt] = (wm * 128 + mt * 32 + (l & 31)) * 128;
#pragma unroll
  for (int nt = 0; nt < 2; ++nt)
    boff[nt] = (wn * 64 + nt * 32 + (l & 31)) * 128;
#pragma unroll
  for (int s = 0; s < 4; ++s)
    soff[s] = ((s * 2 + (l >> 5)) ^ (l & 7)) * 16;

  int32x16 acc[4][2];
#pragma unroll
  for (int mt = 0; mt < 4; ++mt)
#pragma unroll
    for (int nt = 0; nt < 2; ++nt)
#pragma unroll
      for (int r = 0; r < 16; ++r) acc[mt][nt][r] = 0;

  for (int k0 = 0; k0 < K_DIM; k0 += BK) {
    __syncthreads();  // previous iter's LDS reads done
#pragma unroll
    for (int j = 0; j < 8; ++j)
      __builtin_amdgcn_global_load_lds(
          GPTR(gA + (size_t)j * 32 * K_DIM + k0),
          LPTR(As + j * 4096 + w * 1024), 16, 0, 0);
#pragma unroll
    for (int j = 0; j < 4; ++j)
      __builtin_amdgcn_global_load_lds(
          GPTR(gB + (size_t)j * 32 * K_DIM + k0),
          LPTR(Bs + j * 4096 + w * 1024), 16, 0, 0);
    __syncthreads();  // drain vmcnt(0) before reads

#pragma unroll
    for (int s = 0; s < 4; ++s) {
      int32x4 af[4], bf[2];
#pragma unroll
      for (int mt = 0; mt < 4; ++mt)
        af[mt] = *(const int32x4*)(As + aoff[mt] + soff[s]);
#pragma unroll
      for (int nt = 0; nt < 2; ++nt)
        bf[nt] = *(const int32x4*)(Bs + boff[nt] + soff[s]);
#pragma unroll
      for (int mt = 0; mt < 4; ++mt)
#pragma unroll
        for (int nt = 0; nt < 2; ++nt)
          acc[mt][nt] = __builtin_amdgcn_mfma_i32_32x32x32_i8(
              af[mt], bf[nt], acc[mt][nt], 0, 0, 0);
    }
  }

  // epilogue: y = acc * sx[row] * sk[col] + bq[col]
  // C/D layout (32x32): col = l&31, row = (reg&3) + 8*(reg>>2) + 4*(l>>5)
  float skc[2], bqc[2];
  int cc[2];
#pragma unroll
  for (int nt = 0; nt < 2; ++nt) {
    cc[nt] = colBase + wn * 64 + nt * 32 + (l & 31);
    skc[nt] = sk[cc[nt]];
    bqc[nt] = bq[cc[nt]];
  }
#pragma unroll
  for (int mt = 0; mt < 4; ++mt) {
    const int rbase = rowBase + wm * 128 + mt * 32 + (l >> 5) * 4;
#pragma unroll
    for (int g = 0; g < 4; ++g) {
#pragma unroll
      for (int q = 0; q < 4; ++q) {
        const int r = rbase + q + 8 * g;
        const float sxv = sx[r];
#pragma unroll
        for (int nt = 0; nt < 2; ++nt)
          out[(size_t)r * N_DIM + cc[nt]] =
              (float)acc[mt][nt][g * 4 + q] * (sxv * skc[nt]) + bqc[nt];
      }
    }
  }
}

// ---------- 6. per-row int8 requant of output (in place) ----------
__global__ void requant_kernel(float* __restrict__ y) {
  __shared__ float red[4];
  const int row = blockIdx.x;
  const int t = threadIdx.x;
  float* yr = y + (size_t)row * N_DIM;
  float4 v[4];
  float m = 0.0f;
#pragma unroll
  for (int i = 0; i < 4; ++i) {
    v[i] = *(const float4*)(yr + i * 1024 + t * 4);
    m = fmaxf(m, fmaxf(fmaxf(fabsf(v[i].x), fabsf(v[i].y)),
                       fmaxf(fabsf(v[i].z), fabsf(v[i].w))));
  }
  float amax = block_absmax_256(m, red);
  float s = amax / 127.0f;
  if (s == 0.0f) s = 1.0f;
#pragma unroll
  for (int i = 0; i < 4; ++i) {
    float4 o;
    o.x = rintf(fminf(fmaxf(v[i].x / s, -127.0f), 127.0f)) * s;
    o.y = rintf(fminf(fmaxf(v[i].y / s, -127.0f), 127.0f)) * s;
    o.z = rintf(fminf(fmaxf(v[i].z / s, -127.0f), 127.0f)) * s;
    o.w = rintf(fminf(fmaxf(v[i].w / s, -127.0f), 127.0f)) * s;
    *(float4*)(yr + i * 1024 + t * 4) = o;
  }
}

extern "C" void kernel_launch(void* const* d_in, const int* in_sizes, int n_in,
                              void* d_out, int out_size, void* d_ws, size_t ws_size,
                              hipStream_t stream) {
  (void)in_sizes; (void)n_in; (void)out_size; (void)ws_size;
  const float* x    = (const float*)d_in[0];
  const float* kern = (const float*)d_in[1];
  const float* bias = (const float*)d_in[2];
  float* out = (float*)d_out;

  char* w8 = (char*)d_ws;
  int8_t* qx  = (int8_t*)w8;                       // 32 MiB
  int8_t* qkT = (int8_t*)(w8 + 33554432);          // 16 MiB
  // cmp (512 KiB) overlaps qkT start: dead before quant_kT writes qkT
  float* cmp  = (float*)(w8 + 33554432);
  float* sx   = (float*)(w8 + 50331648);           // 8192 f
  float* sk   = (float*)(w8 + 50331648 + 32768);   // 4096 f
  float* bq   = (float*)(w8 + 50331648 + 49152);   // 4096 f

  quant_x_kernel<<<M_ROWS, 256, 0, stream>>>(x, qx, sx);
  colmax_kernel<<<dim3(16, 32), 256, 0, stream>>>(kern, cmp);
  finalize_kernel<<<17, 256, 0, stream>>>(cmp, sk, bias, bq);
  quant_kT_kernel<<<dim3(64, 64), 256, 0, stream>>>(kern, sk, qkT);
  gemm_kernel<<<dim3(32, 32), 256, 0, stream>>>(qx, qkT, sx, sk, bq, out);
  requant_kernel<<<M_ROWS, 256, 0, stream>>>(out);
}

// Round 3
// 469.102 us; speedup vs baseline: 1.1076x; 1.0338x over previous
//
#include <hip/hip_runtime.h>
#include <stdint.h>

typedef int int32x4 __attribute__((ext_vector_type(4)));

#define M_ROWS 8192
#define K_DIM  4096
#define N_DIM  4096

#define GPTR(p) ((const __attribute__((address_space(1))) unsigned int*)(p))
#define LPTR(p) ((__attribute__((address_space(3))) unsigned int*)(p))

// ---------- shared helper: block-wide absmax over 256 threads ----------
__device__ __forceinline__ float block_absmax_256(float v, float* red) {
#pragma unroll
  for (int off = 32; off > 0; off >>= 1)
    v = fmaxf(v, __shfl_down(v, off, 64));
  const int w = threadIdx.x >> 6;
  if ((threadIdx.x & 63) == 0) red[w] = v;
  __syncthreads();
  return fmaxf(fmaxf(red[0], red[1]), fmaxf(red[2], red[3]));
}

// ---------- 1. per-row quantize x -> int8 + scale (coalesced, 1 div/thread) ----------
__global__ void quant_x_kernel(const float* __restrict__ x,
                               int8_t* __restrict__ qx,
                               float* __restrict__ sx) {
  __shared__ float red[4];
  const int row = blockIdx.x;
  const int t = threadIdx.x;
  const float4* xr = (const float4*)(x + (size_t)row * K_DIM);
  float4 v[4];
  float m = 0.0f;
#pragma unroll
  for (int i = 0; i < 4; ++i) {
    v[i] = xr[i * 256 + t];  // lanes contiguous 16 B -> coalesced
    m = fmaxf(m, fmaxf(fmaxf(fabsf(v[i].x), fabsf(v[i].y)),
                       fmaxf(fabsf(v[i].z), fabsf(v[i].w))));
  }
  float amax = block_absmax_256(m, red);
  float scale = amax / 127.0f;
  float inv;
  if (scale == 0.0f) { scale = 1.0f; inv = 1.0f; }
  else inv = 1.0f / scale;
  if (t == 0) sx[row] = scale;
  int* qw = (int*)(qx + (size_t)row * K_DIM);
#pragma unroll
  for (int i = 0; i < 4; ++i) {
    float a = fminf(fmaxf(v[i].x * inv, -127.0f), 127.0f);
    float b = fminf(fmaxf(v[i].y * inv, -127.0f), 127.0f);
    float c = fminf(fmaxf(v[i].z * inv, -127.0f), 127.0f);
    float d = fminf(fmaxf(v[i].w * inv, -127.0f), 127.0f);
    int qa = (int)rintf(a), qb = (int)rintf(b), qc = (int)rintf(c), qd = (int)rintf(d);
    qw[i * 256 + t] =
        (qa & 255) | ((qb & 255) << 8) | ((qc & 255) << 16) | ((qd & 255) << 24);
  }
}

// ---------- 2. per-column partial absmax of kernel (no atomics, no memset) ----------
__global__ void colmax_kernel(const float* __restrict__ k,
                              float* __restrict__ cmp) {
  const int c = blockIdx.x * 256 + threadIdx.x;
  const int r0 = blockIdx.y * 128;
  float m = 0.0f;
  for (int i = 0; i < 128; ++i)
    m = fmaxf(m, fabsf(k[(size_t)(r0 + i) * N_DIM + c]));
  cmp[(size_t)blockIdx.y * N_DIM + c] = m;  // partial max, reduced in finalize
}

// ---------- 3. finalize: sk + reciprocal rsk; bias int16 fake-quant ----------
__global__ void finalize_kernel(const float* __restrict__ cmp,
                                float* __restrict__ sk,
                                float* __restrict__ rsk,
                                const float* __restrict__ bias,
                                float* __restrict__ bq) {
  __shared__ float red[4];
  const int t = threadIdx.x;
  if (blockIdx.x < 16) {
    const int c = blockIdx.x * 256 + t;
    float m = 0.0f;
#pragma unroll
    for (int i = 0; i < 32; ++i) m = fmaxf(m, cmp[(size_t)i * N_DIM + c]);
    float s = m / 127.0f;
    float r;
    if (s == 0.0f) { s = 1.0f; r = 1.0f; }
    else r = 1.0f / s;
    sk[c] = s;
    rsk[c] = r;
  } else {
    float4 v[4];
    float m = 0.0f;
#pragma unroll
    for (int i = 0; i < 4; ++i) {
      v[i] = *(const float4*)(bias + t * 16 + i * 4);
      m = fmaxf(m, fmaxf(fmaxf(fabsf(v[i].x), fabsf(v[i].y)),
                         fmaxf(fabsf(v[i].z), fabsf(v[i].w))));
    }
    float amax = block_absmax_256(m, red);
    float s = amax / 32767.0f;
    float inv;
    if (s == 0.0f) { s = 1.0f; inv = 1.0f; }
    else inv = 1.0f / s;
#pragma unroll
    for (int i = 0; i < 4; ++i) {
      float4 o;
      o.x = rintf(fminf(fmaxf(v[i].x * inv, -32767.0f), 32767.0f)) * s;
      o.y = rintf(fminf(fmaxf(v[i].y * inv, -32767.0f), 32767.0f)) * s;
      o.z = rintf(fminf(fmaxf(v[i].z * inv, -32767.0f), 32767.0f)) * s;
      o.w = rintf(fminf(fmaxf(v[i].w * inv, -32767.0f), 32767.0f)) * s;
      *(float4*)(bq + t * 16 + i * 4) = o;
    }
  }
}

// ---------- 4. quantize kernel per-col and transpose -> qkT[F][D] int8 ----------
__global__ void quant_kT_kernel(const float* __restrict__ kern,
                                const float* __restrict__ rsk,
                                int8_t* __restrict__ qkT) {
  __shared__ int8_t tile[64][80];
  const int t = threadIdx.x;
  const int c0 = blockIdx.x * 64;
  const int r0 = blockIdx.y * 64;
  const int colg = (t & 15) * 4;
  const int row = t >> 4;
  float r4[4];
#pragma unroll
  for (int j = 0; j < 4; ++j) r4[j] = rsk[c0 + colg + j];
#pragma unroll
  for (int i = 0; i < 4; ++i) {
    const int r = row + i * 16;
    float4 v = *(const float4*)&kern[(size_t)(r0 + r) * N_DIM + c0 + colg];
    tile[colg + 0][r] = (int8_t)rintf(fminf(fmaxf(v.x * r4[0], -127.0f), 127.0f));
    tile[colg + 1][r] = (int8_t)rintf(fminf(fmaxf(v.y * r4[1], -127.0f), 127.0f));
    tile[colg + 2][r] = (int8_t)rintf(fminf(fmaxf(v.z * r4[2], -127.0f), 127.0f));
    tile[colg + 3][r] = (int8_t)rintf(fminf(fmaxf(v.w * r4[3], -127.0f), 127.0f));
  }
  __syncthreads();
  const int f = t >> 2;
  const int seg = (t & 3) * 16;
  int4 w = *(const int4*)&tile[f][seg];
  *(int4*)(qkT + (size_t)(c0 + f) * K_DIM + r0 + seg) = w;
}

// ---------- 5. int8 GEMM 8192x4096x4096 + scale/bias epilogue ----------
// Round-0 proven version, byte-for-byte: 128x128x128 tile, 16x16x64 MFMA,
// chunk^(row&7) swizzle (measured 0 bank conflicts), width-16 DMA staging,
// 2 barriers/K-step. 135 us / MfmaUtil 48% measured.
#define BM 128
#define BN 128
#define BK 128

__global__ void gemm_kernel(const int8_t* __restrict__ qx,
                            const int8_t* __restrict__ qkT,
                            const float* __restrict__ sx,
                            const float* __restrict__ sk,
                            const float* __restrict__ bq,
                            float* __restrict__ out) {
  __shared__ int32x4 AsV[1024];  // 16 KiB: A tile [128 rows][128 bytes]
  __shared__ int32x4 BsV[1024];  // 16 KiB: B tile [128 cols][128 bytes]
  char* As = (char*)AsV;
  char* Bs = (char*)BsV;

  const int t = threadIdx.x;
  const int w = t >> 6;
  const int l = t & 63;
  const int wm = w >> 1, wn = w & 1;
  const int rowBase = blockIdx.y * BM;
  const int colBase = blockIdx.x * BN;

  // XOR swizzle, 8 slots of 16 B per 128-B row: global k-chunk g lives at
  // LDS slot g ^ (row & 7).
  const int8_t* gA = qx  + (size_t)(rowBase + (l >> 3)) * K_DIM
                         + (((l & 7) ^ (l >> 3)) * 16);
  const int8_t* gB = qkT + (size_t)(colBase + (l >> 3)) * K_DIM
                         + (((l & 7) ^ (l >> 3)) * 16);

  int arow[4], brow[4], soff[2];
#pragma unroll
  for (int mt = 0; mt < 4; ++mt)
    arow[mt] = (wm * 64 + mt * 16 + (l & 15)) * 128;
#pragma unroll
  for (int nt = 0; nt < 4; ++nt)
    brow[nt] = (wn * 64 + nt * 16 + (l & 15)) * 128;
#pragma unroll
  for (int s = 0; s < 2; ++s)
    soff[s] = ((s * 4 + (l >> 4)) ^ (l & 7)) * 16;

  int32x4 zero = {0, 0, 0, 0};
  int32x4 acc[4][4];
#pragma unroll
  for (int mt = 0; mt < 4; ++mt)
#pragma unroll
    for (int nt = 0; nt < 4; ++nt) acc[mt][nt] = zero;

  for (int k0 = 0; k0 < K_DIM; k0 += BK) {
    __syncthreads();  // previous iter's LDS reads done
#pragma unroll
    for (int j = 0; j < 4; ++j) {
      const int ca = j * 4 + w;  // 16 chunks of 8 rows x 128 B
      __builtin_amdgcn_global_load_lds(
          GPTR(gA + (size_t)ca * 8 * K_DIM + k0),
          LPTR(As + ca * 1024), 16, 0, 0);
      __builtin_amdgcn_global_load_lds(
          GPTR(gB + (size_t)ca * 8 * K_DIM + k0),
          LPTR(Bs + ca * 1024), 16, 0, 0);
    }
    __syncthreads();  // drain vmcnt(0) before reads

#pragma unroll
    for (int s = 0; s < 2; ++s) {
      int32x4 af[4], bf[4];
#pragma unroll
      for (int mt = 0; mt < 4; ++mt)
        af[mt] = *(const int32x4*)(As + arow[mt] + soff[s]);
#pragma unroll
      for (int nt = 0; nt < 4; ++nt)
        bf[nt] = *(const int32x4*)(Bs + brow[nt] + soff[s]);
#pragma unroll
      for (int mt = 0; mt < 4; ++mt)
#pragma unroll
        for (int nt = 0; nt < 4; ++nt)
          acc[mt][nt] = __builtin_amdgcn_mfma_i32_16x16x64_i8(
              af[mt], bf[nt], acc[mt][nt], 0, 0, 0);
    }
  }

  // epilogue: y = acc * sx[row] * sk[col] + bq[col]   (fp32 to d_out)
  const int lr = (l >> 4) * 4;
  const int lc = l & 15;
#pragma unroll
  for (int mt = 0; mt < 4; ++mt) {
    const int r0 = rowBase + wm * 64 + mt * 16 + lr;
    float sxr[4];
#pragma unroll
    for (int r = 0; r < 4; ++r) sxr[r] = sx[r0 + r];
#pragma unroll
    for (int nt = 0; nt < 4; ++nt) {
      const int c = colBase + wn * 64 + nt * 16 + lc;
      const float skc = sk[c];
      const float bqc = bq[c];
#pragma unroll
      for (int r = 0; r < 4; ++r)
        out[(size_t)(r0 + r) * N_DIM + c] =
            (float)acc[mt][nt][r] * (sxr[r] * skc) + bqc;
    }
  }
}

// ---------- 6. per-row int8 requant of output (in place, 1 div/thread) ----------
__global__ void requant_kernel(float* __restrict__ y) {
  __shared__ float red[4];
  const int row = blockIdx.x;
  const int t = threadIdx.x;
  float* yr = y + (size_t)row * N_DIM;
  float4 v[4];
  float m = 0.0f;
#pragma unroll
  for (int i = 0; i < 4; ++i) {
    v[i] = *(const float4*)(yr + i * 1024 + t * 4);
    m = fmaxf(m, fmaxf(fmaxf(fabsf(v[i].x), fabsf(v[i].y)),
                       fmaxf(fabsf(v[i].z), fabsf(v[i].w))));
  }
  float amax = block_absmax_256(m, red);
  float s = amax / 127.0f;
  float inv;
  if (s == 0.0f) { s = 1.0f; inv = 1.0f; }
  else inv = 1.0f / s;
#pragma unroll
  for (int i = 0; i < 4; ++i) {
    float4 o;
    o.x = rintf(fminf(fmaxf(v[i].x * inv, -127.0f), 127.0f)) * s;
    o.y = rintf(fminf(fmaxf(v[i].y * inv, -127.0f), 127.0f)) * s;
    o.z = rintf(fminf(fmaxf(v[i].z * inv, -127.0f), 127.0f)) * s;
    o.w = rintf(fminf(fmaxf(v[i].w * inv, -127.0f), 127.0f)) * s;
    *(float4*)(yr + i * 1024 + t * 4) = o;
  }
}

extern "C" void kernel_launch(void* const* d_in, const int* in_sizes, int n_in,
                              void* d_out, int out_size, void* d_ws, size_t ws_size,
                              hipStream_t stream) {
  (void)in_sizes; (void)n_in; (void)out_size; (void)ws_size;
  const float* x    = (const float*)d_in[0];
  const float* kern = (const float*)d_in[1];
  const float* bias = (const float*)d_in[2];
  float* out = (float*)d_out;

  char* w8 = (char*)d_ws;
  int8_t* qx  = (int8_t*)w8;                       // 32 MiB
  int8_t* qkT = (int8_t*)(w8 + 33554432);          // 16 MiB
  // cmp (512 KiB) overlaps qkT start: dead before quant_kT writes qkT
  float* cmp  = (float*)(w8 + 33554432);
  float* sx   = (float*)(w8 + 50331648);           // 8192 f
  float* sk   = (float*)(w8 + 50331648 + 32768);   // 4096 f
  float* bq   = (float*)(w8 + 50331648 + 49152);   // 4096 f
  float* rsk  = (float*)(w8 + 50331648 + 65536);   // 4096 f

  quant_x_kernel<<<M_ROWS, 256, 0, stream>>>(x, qx, sx);
  colmax_kernel<<<dim3(16, 32), 256, 0, stream>>>(kern, cmp);
  finalize_kernel<<<17, 256, 0, stream>>>(cmp, sk, rsk, bias, bq);
  quant_kT_kernel<<<dim3(64, 64), 256, 0, stream>>>(kern, rsk, qkT);
  gemm_kernel<<<dim3(N_DIM / BN, M_ROWS / BM), 256, 0, stream>>>(qx, qkT, sx, sk, bq, out);
  requant_kernel<<<M_ROWS, 256, 0, stream>>>(out);
}